// Round 7
// baseline (717.645 us; speedup 1.0000x reference)
//
#include <hip/hip_runtime.h>

// MultiScaleRetention. Inputs f32, output f32.
// B=2 T=2048 D=2048 H=8 DK=256 DV=512 C=64, N_chunks=32.
// R7: retention restructured: vt=16 (grid 512 -> 2 blocks/CU), LDS-only
// barriers (s_waitcnt lgkmcnt(0)+s_barrier, no vmcnt drain), v double-
// buffered across chunks. GEMMs/rotary_scores/norm_gate unchanged from R6.
// ws (u16): P[2.1M] q[8.4M] k[8.4M] kT[8.4M] v[16.8M] o[16.8M] xb[8.4M]
//   = 138.6MB. g aliases q+k; on aliases v; weight tmp aliases kT.

typedef unsigned short u16;
typedef unsigned int u32;
typedef short bf16x8 __attribute__((ext_vector_type(8)));
typedef short s16x4 __attribute__((ext_vector_type(4)));
typedef float f32x4 __attribute__((ext_vector_type(4)));
typedef u32 u32x2 __attribute__((ext_vector_type(2)));
typedef u32 u32x4 __attribute__((ext_vector_type(4)));

typedef __attribute__((address_space(3))) u32 lds_u32;
typedef __attribute__((address_space(1))) const u32 gbl_u32;

__device__ __forceinline__ float bf2f(u16 u) {
    union { u32 i; float f; } x; x.i = ((u32)u) << 16; return x.f;
}
__device__ __forceinline__ u16 f2bf(float f) {
    union { float f; u32 i; } x; x.f = f;
    u32 u = x.i;
    u += 0x7fffu + ((u >> 16) & 1u);   // RNE (finite only)
    return (u16)(u >> 16);
}
__device__ __forceinline__ f32x4 mfma16(bf16x8 a, bf16x8 b, f32x4 c) {
    return __builtin_amdgcn_mfma_f32_16x16x32_bf16(a, b, c, 0, 0, 0);
}
__device__ __forceinline__ void gload16(const u16* g, u16* lds) {
    __builtin_amdgcn_global_load_lds((gbl_u32*)(unsigned long long)g,
                                     (lds_u32*)(u32)(unsigned long long)lds, 16, 0, 0);
}
// Barrier with LDS-only drain: cross-wave deps in retention are LDS (St/vsT);
// VMEM loads are same-wave consumed (compiler inserts vmcnt at use).
__device__ __forceinline__ void bar_lds() {
    __asm__ volatile("s_waitcnt lgkmcnt(0)\n\ts_barrier" ::: "memory");
}

// ---------------------------------------------------------------------------
// f32 -> bf16 bulk convert. 8 elems/thread.
// ---------------------------------------------------------------------------
__global__ __launch_bounds__(256)
void cvt_bf16(const float* __restrict__ src, u16* __restrict__ dst)
{
    size_t i = ((size_t)blockIdx.x * 256 + threadIdx.x) * 8;
    f32x4 a = *(const f32x4*)(src + i);
    f32x4 b = *(const f32x4*)(src + i + 4);
    bf16x8 r;
#pragma unroll
    for (int j = 0; j < 4; j++) { r[j] = (short)f2bf(a[j]); r[j + 4] = (short)f2bf(b[j]); }
    *(bf16x8*)(dst + i) = r;
}

// ---------------------------------------------------------------------------
// NT GEMM: C[M][N] = A[M][K](bf16) @ B[N][K](bf16)^T, fp32 acc, C bf16/f32.
// grid=(N/128, M/128), block=256. 128x128 tile, BK=64, global_load_lds DMA.
// ---------------------------------------------------------------------------
template<bool CF32>
__global__ __launch_bounds__(256, 2)
void gemm_bt(const u16* __restrict__ A, const u16* __restrict__ Bm,
             void* __restrict__ Cv, int N, int K)
{
    __shared__ u16 Ab[128 * 64];
    __shared__ u16 Bb[128 * 64];
    const int tid = threadIdx.x;
    const int lane = tid & 63, wave = tid >> 6;
    const int quad = lane >> 4, l16 = lane & 15;
    const int tn = blockIdx.x, tm = blockIdx.y;
    const int wr = wave >> 1, wc = wave & 1;

    f32x4 acc[4][4];
#pragma unroll
    for (int i = 0; i < 4; i++)
#pragma unroll
        for (int j = 0; j < 4; j++) acc[i][j] = (f32x4){0.f, 0.f, 0.f, 0.f};

    const u16* Abase = A + (size_t)tm * 128 * K;
    const u16* Bbase = Bm + (size_t)tn * 128 * K;
    const int rsub = lane >> 3, csub = (lane & 7) * 8;

    for (int k0 = 0; k0 < K; k0 += 64) {
        __syncthreads();
#pragma unroll
        for (int i = 0; i < 4; i++) {
            int chunk = wave * 4 + i;
            int r = chunk * 8 + rsub;
            gload16(Abase + (size_t)r * K + k0 + csub, Ab + chunk * 512);
            gload16(Bbase + (size_t)r * K + k0 + csub, Bb + chunk * 512);
        }
        __syncthreads();
#pragma unroll
        for (int kc = 0; kc < 2; kc++) {
            bf16x8 af[4], bfr[4];
#pragma unroll
            for (int mt = 0; mt < 4; mt++)
                af[mt] = *(const bf16x8*)(Ab + (wr * 64 + mt * 16 + l16) * 64 + kc * 32 + quad * 8);
#pragma unroll
            for (int nt = 0; nt < 4; nt++)
                bfr[nt] = *(const bf16x8*)(Bb + (wc * 64 + nt * 16 + l16) * 64 + kc * 32 + quad * 8);
#pragma unroll
            for (int mt = 0; mt < 4; mt++)
#pragma unroll
                for (int nt = 0; nt < 4; nt++)
                    acc[mt][nt] = mfma16(af[mt], bfr[nt], acc[mt][nt]);
        }
    }
    const int row0 = tm * 128 + wr * 64 + quad * 4;
    const int col0 = tn * 128 + wc * 64 + l16;
#pragma unroll
    for (int mt = 0; mt < 4; mt++)
#pragma unroll
        for (int nt = 0; nt < 4; nt++)
#pragma unroll
            for (int r = 0; r < 4; r++) {
                size_t idx = (size_t)(row0 + mt * 16 + r) * N + col0 + nt * 16;
                if constexpr (CF32) ((float*)Cv)[idx] = acc[mt][nt][r];
                else                ((u16*)Cv)[idx]   = f2bf(acc[mt][nt][r]);
            }
}

// ---------------------------------------------------------------------------
// Fused rotary + scores + kT. grid = 512 (bx = n*16 + bh), block 256.
// ---------------------------------------------------------------------------
__global__ __launch_bounds__(256, 2)
void rotary_scores(u16* __restrict__ q, const u16* __restrict__ k,
                   u16* __restrict__ kT, u16* __restrict__ P)
{
    __shared__ u16 qS[64 * 264];
    __shared__ u16 kS[64 * 264];
    const int tid = threadIdx.x;
    const int lane = tid & 63, wave = tid >> 6;
    const int quad = lane >> 4, l16 = lane & 15;
    const int bx = blockIdx.x;
    const int bh = bx & 15, n = bx >> 4;
    const int b = bh >> 3, h = bh & 7;
    const int t0 = n * 64;

    const int row = tid >> 2;
    const int j0 = (tid & 3) * 32;
    const size_t rowbase = (size_t)(b * 2048 + t0 + row) * 2048 + h * 256;
    const float tpos = (float)(t0 + row);
#pragma unroll
    for (int i = 0; i < 4; i++) {
        int j = j0 + i * 8;
        bf16x8 x1 = *(const bf16x8*)(q + rowbase + j);
        bf16x8 x2 = *(const bf16x8*)(q + rowbase + j + 128);
        bf16x8 y1 = *(const bf16x8*)(k + rowbase + j);
        bf16x8 y2 = *(const bf16x8*)(k + rowbase + j + 128);
        bf16x8 o1, o2, p1, p2;
#pragma unroll
        for (int e = 0; e < 8; e++) {
            float inv = expf((-9.210340371976184f / 128.f) * (float)(j + e));
            float ang = tpos * inv;
            float sv = sinf(ang), cv = cosf(ang);
            float a = bf2f((u16)x1[e]), bb = bf2f((u16)x2[e]);
            o1[e] = (short)f2bf((a * cv - bb * sv) * 0.0625f);
            o2[e] = (short)f2bf((bb * cv + a * sv) * 0.0625f);
            float e1 = bf2f((u16)y1[e]), e2 = bf2f((u16)y2[e]);
            p1[e] = (short)f2bf(e1 * cv - e2 * sv);
            p2[e] = (short)f2bf(e2 * cv + e1 * sv);
        }
        *(bf16x8*)(q + rowbase + j)       = o1;
        *(bf16x8*)(q + rowbase + j + 128) = o2;
        *(bf16x8*)(qS + row * 264 + j)       = o1;
        *(bf16x8*)(qS + row * 264 + j + 128) = o2;
        *(bf16x8*)(kS + row * 264 + j)       = p1;
        *(bf16x8*)(kS + row * 264 + j + 128) = p2;
    }
    __syncthreads();

    const float logb = logf(1.0f - exp2f(-5.0f - (float)h));
    f32x4 sc[4];
#pragma unroll
    for (int i = 0; i < 4; i++) sc[i] = (f32x4){0.f, 0.f, 0.f, 0.f};
#pragma unroll
    for (int kc = 0; kc < 8; kc++) {
        bf16x8 af = *(const bf16x8*)(qS + (wave * 16 + l16) * 264 + kc * 32 + quad * 8);
#pragma unroll
        for (int mt = 0; mt < 4; mt++) {
            bf16x8 bk = *(const bf16x8*)(kS + (mt * 16 + l16) * 264 + kc * 32 + quad * 8);
            sc[mt] = mfma16(af, bk, sc[mt]);
        }
    }
    u16* Pb = P + ((size_t)(bh * 32 + n)) * 64 * 64;
#pragma unroll
    for (int r = 0; r < 4; r++) {
        int cr = wave * 16 + quad * 4 + r;
        float rowe = __expf(logb * (float)(cr - 63));
#pragma unroll
        for (int mt = 0; mt < 4; mt++) {
            int m = mt * 16 + l16;
            float val = (cr >= m) ? sc[mt][r] * rowe : 0.0f;
            Pb[cr * 64 + m] = f2bf(val);
        }
    }

    const int d = tid;
    u16* dst = kT + ((size_t)(bh * 256 + d)) * 2048 + t0;
#pragma unroll
    for (int g8 = 0; g8 < 8; g8++) {
        bf16x8 w;
#pragma unroll
        for (int e = 0; e < 8; e++) w[e] = (short)kS[(g8 * 8 + e) * 264 + d];
        *(bf16x8*)(dst + g8 * 8) = w;
    }
}

// ---------------------------------------------------------------------------
// Retention scan (inter + state update + PV; P precomputed).
// grid = 512 (bx = vt*16 + bh; vt<32 a 16-wide DV slice), block 512 (8 waves),
// 2 blocks/CU. Waves 0-3: inter/PV/O for c-tile = wave. All 8 waves: state
// d-band [wave*32,+32). S in fp32 regs; LDS: St[16][264] (bf16 mirror),
// vsT[16][72]. LDS-only barriers; v double-buffered across chunks; q/kT/P
// prefetched at loop top (vmcnt waits land at use, not at the barrier).
// ---------------------------------------------------------------------------
__global__ __launch_bounds__(512, 2)
void retention(const u16* __restrict__ Q, const u16* __restrict__ KT,
               const u16* __restrict__ V, const u16* __restrict__ P,
               u16* __restrict__ O)
{
    __shared__ u16 St[16 * 264];
    __shared__ u16 vsT[16 * 72];

    const int tid = threadIdx.x;
    const int lane = tid & 63, wave = tid >> 6;
    const int quad = lane >> 4, l16 = lane & 15;
    const int bx = blockIdx.x;
    const int bh = bx & 15, vt = bx >> 4;      // vt < 32
    const int b = bh >> 3, h = bh & 7;

    const float logb = logf(1.0f - exp2f(-5.0f - (float)h));
    const float cdec = __expf(logb * 64.0f);

    int cr[4];
    float qdecr[4];
#pragma unroll
    for (int r = 0; r < 4; r++) {
        cr[r] = wave * 16 + quad * 4 + r;              // valid for wave<4
        qdecr[r] = __expf(logb * (float)(cr[r] + 1));
    }
    const int mv = tid >> 3;                  // 0..63 v-stage row
    const int vc2 = (tid & 7) * 2;            // 0..14 v-stage col pair
    const float kdv = __expf(logb * (float)(63 - mv));

    for (int i = tid; i < 16 * 264; i += 512) St[i] = 0;

    f32x4 Sacc[2];
    Sacc[0] = (f32x4){0.f, 0.f, 0.f, 0.f};
    Sacc[1] = (f32x4){0.f, 0.f, 0.f, 0.f};

    const u16* vptr0 = V + (size_t)(b * 2048 + mv) * 4096 + h * 512 + vt * 16 + vc2;
    u32 vv = *(const u32*)vptr0;              // chunk 0's v (double-buffered)

    for (int n = 0; n < 32; n++) {
        const int t0 = n * 64;
        // ---- prefetch this chunk's A-operands (L2-hot; waits land at use) ----
        bf16x8 qf[8], pf[2];
        if (wave < 4) {
#pragma unroll
            for (int kc = 0; kc < 8; kc++)
                qf[kc] = *(const bf16x8*)(Q + (size_t)(b * 2048 + t0 + wave * 16 + l16) * 2048
                                          + h * 256 + kc * 32 + quad * 8);
#pragma unroll
            for (int kc2 = 0; kc2 < 2; kc2++)
                pf[kc2] = *(const bf16x8*)(P + ((size_t)(bh * 32 + n) * 64 + wave * 16 + l16) * 64
                                           + kc2 * 32 + quad * 8);
        }
        bf16x8 ktf[2][2];
#pragma unroll
        for (int dt = 0; dt < 2; dt++)
#pragma unroll
            for (int kc2 = 0; kc2 < 2; kc2++)
                ktf[dt][kc2] = *(const bf16x8*)(KT + (size_t)(bh * 256 + wave * 32 + dt * 16 + l16) * 2048
                                                + t0 + kc2 * 32 + quad * 8);

        bar_lds();   // [A] St(n-1) writes visible; prev vsT reads done

        // stage vsT = v * kdec[m] (transposed [v][m]) from double-buffered vv
        vsT[(vc2 + 0) * 72 + mv] = f2bf(bf2f((u16)(vv & 0xffff)) * kdv);
        vsT[(vc2 + 1) * 72 + mv] = f2bf(bf2f((u16)(vv >> 16)) * kdv);
        // issue next chunk's v load now (full chunk of slack to cover HBM)
        if (n < 31) vv = *(const u32*)(vptr0 + (size_t)(t0 + 64) * 4096);

        // inter: o = q @ S_{n-1}
        f32x4 oacc = (f32x4){0.f, 0.f, 0.f, 0.f};
        if (wave < 4) {
#pragma unroll
            for (int kc = 0; kc < 8; kc++) {
                bf16x8 bs = *(const bf16x8*)(St + l16 * 264 + kc * 32 + quad * 8);
                oacc = mfma16(qf[kc], bs, oacc);
            }
        }

        bar_lds();   // [B] vsT visible; all St reads done

        // update: S = S*cdec + kT @ vs (all waves, own d-band)
#pragma unroll
        for (int dt = 0; dt < 2; dt++)
#pragma unroll
            for (int e = 0; e < 4; e++) Sacc[dt][e] *= cdec;
#pragma unroll
        for (int kc2 = 0; kc2 < 2; kc2++) {
            bf16x8 bv = *(const bf16x8*)(vsT + l16 * 72 + kc2 * 32 + quad * 8);
#pragma unroll
            for (int dt = 0; dt < 2; dt++)
                Sacc[dt] = mfma16(ktf[dt][kc2], bv, Sacc[dt]);
        }
        if (wave < 4) {
            // scale inter by q_dec, add PV
#pragma unroll
            for (int r = 0; r < 4; r++) oacc[r] *= qdecr[r];
#pragma unroll
            for (int kc2 = 0; kc2 < 2; kc2++) {
                bf16x8 bv = *(const bf16x8*)(vsT + l16 * 72 + kc2 * 32 + quad * 8);
                oacc = mfma16(pf[kc2], bv, oacc);
            }
#pragma unroll
            for (int r = 0; r < 4; r++)
                O[(size_t)(b * 2048 + t0 + cr[r]) * 4096 + h * 512 + vt * 16 + l16] =
                    f2bf(oacc[r]);
        }
        // St refresh (S_n)
#pragma unroll
        for (int dt = 0; dt < 2; dt++) {
            s16x4 w;
#pragma unroll
            for (int r = 0; r < 4; r++) w[r] = (short)f2bf(Sacc[dt][r]);
            *(s16x4*)(St + l16 * 264 + wave * 32 + dt * 16 + quad * 4) = w;
        }
    }
}

// ---------------------------------------------------------------------------
// RMSNorm over DV=512 per (b,t,h) row, * g_norm_weight(f32), * silu(g).
// ---------------------------------------------------------------------------
__global__ __launch_bounds__(256)
void norm_gate(const u16* __restrict__ O, const u16* __restrict__ G,
               const float* __restrict__ gw, u16* __restrict__ ON)
{
    const int lane = threadIdx.x & 63;
    const size_t row = (size_t)blockIdx.x * 4 + (threadIdx.x >> 6);
    bf16x8 ov = *(const bf16x8*)(O + row * 512 + lane * 8);
    bf16x8 gv = *(const bf16x8*)(G + row * 512 + lane * 8);
    f32x4 w0 = *(const f32x4*)(gw + lane * 8);
    f32x4 w1 = *(const f32x4*)(gw + lane * 8 + 4);
    float of[8], gf[8];
    float ss = 0.f;
#pragma unroll
    for (int j = 0; j < 8; j++) {
        of[j] = bf2f((u16)ov[j]);
        gf[j] = bf2f((u16)gv[j]);
        ss += of[j] * of[j];
    }
#pragma unroll
    for (int off = 32; off > 0; off >>= 1) ss += __shfl_down(ss, off);
    ss = __shfl(ss, 0);
    const float rms = rsqrtf(ss * (1.0f / 512.0f) + 1e-5f);
    bf16x8 res;
#pragma unroll
    for (int j = 0; j < 8; j++) {
        float wj = (j < 4) ? w0[j] : w1[j - 4];
        float xn = of[j] * rms * wj;
        float sg = gf[j] / (1.f + __expf(-gf[j]));
        res[j] = (short)f2bf(xn * sg);
    }
    *(bf16x8*)(ON + row * 512 + lane * 8) = res;
}

// ---------------------------------------------------------------------------
extern "C" void kernel_launch(void* const* d_in, const int* in_sizes, int n_in,
                              void* d_out, int out_size, void* d_ws, size_t ws_size,
                              hipStream_t stream)
{
    const float* x  = (const float*)d_in[0];
    const float* Wq = (const float*)d_in[1];
    const float* Wk = (const float*)d_in[2];
    const float* Wv = (const float*)d_in[3];
    const float* Wg = (const float*)d_in[4];
    const float* Wo = (const float*)d_in[5];
    const float* gw = (const float*)d_in[6];
    float* out = (float*)d_out;

    const size_t M8 = (size_t)4096 * 2048;     // 8.4M u16
    u16* Pb = (u16*)d_ws;                      // 2.1M u16
    u16* q  = Pb + (size_t)16 * 32 * 64 * 64;
    u16* k  = q + M8;
    u16* kT = k + M8;
    u16* v  = kT + M8;                         // 16.8M
    u16* o  = v + 2 * M8;                      // 16.8M
    u16* xb = o + 2 * M8;                      // 8.4M
    u16* g  = q;                               // alias q+k (dead after retention)
    u16* on = v;                               // alias v (dead after retention)
    u16* wt = kT;                              // weight tmp (kT slot)

    dim3 blk(256, 1, 1), blk512(512, 1, 1);
    cvt_bf16<<<dim3(4096, 1, 1), blk, 0, stream>>>(x, xb);

    cvt_bf16<<<dim3(2048, 1, 1), blk, 0, stream>>>(Wq, wt);
    gemm_bt<false><<<dim3(16, 32, 1), blk, 0, stream>>>(xb, wt, q, 2048, 2048);
    cvt_bf16<<<dim3(2048, 1, 1), blk, 0, stream>>>(Wk, wt);
    gemm_bt<false><<<dim3(16, 32, 1), blk, 0, stream>>>(xb, wt, k, 2048, 2048);
    cvt_bf16<<<dim3(4096, 1, 1), blk, 0, stream>>>(Wv, wt);
    gemm_bt<false><<<dim3(32, 32, 1), blk, 0, stream>>>(xb, wt, v, 4096, 2048);

    rotary_scores<<<dim3(512, 1, 1), blk, 0, stream>>>(q, k, kT, Pb);
    retention<<<dim3(512, 1, 1), blk512, 0, stream>>>(q, kT, v, Pb, o);

    cvt_bf16<<<dim3(4096, 1, 1), blk, 0, stream>>>(Wg, kT);       // kT dead
    gemm_bt<false><<<dim3(32, 32, 1), blk, 0, stream>>>(xb, kT, g, 4096, 2048);
    norm_gate<<<dim3(8192, 1, 1), blk, 0, stream>>>(o, g, gw, on);
    cvt_bf16<<<dim3(4096, 1, 1), blk, 0, stream>>>(Wo, kT);
    gemm_bt<true><<<dim3(16, 32, 1), blk, 0, stream>>>(on, kT, out, 2048, 4096);
}